// Round 11
// baseline (204.678 us; speedup 1.0000x reference)
//
#include <hip/hip_runtime.h>
#include <hip/hip_bf16.h>
#include <hip/hip_fp16.h>

#define SEQ_T 100
#define HID 20
#define EMB_D 50
#define VOCAB_N 50000
#define TABW 60          // tab row stride = 60 gate cols [z20|r20|h20]
#define NTILE 3125       // VOCAB_N/16
#define BBLK 782         // build_table blocks (x4 waves, 1 tile/wave)

typedef short sh8 __attribute__((ext_vector_type(8)));   // 8 bf16 bit patterns
typedef float f4  __attribute__((ext_vector_type(4)));

// ws layout (float/dword offsets). tab f16: 50000*60*2B = 6 MB.
#define OFF_U1P 0        // 600 dwords (60 cols x 10 packed f16 k-pairs, PRESCALED)
#define OFF_W2P 600
#define OFF_U2P 1200
#define OFF_B1  3600     // 120 fp32 (first 60 raw bi1 for build MFMA; last 60 br1 prescaled)
#define OFF_B2  3720     // 120 fp32 (all prescaled)
#define OFF_WD  3840     // 300 fp32
#define OFF_BD  4140     // 15 fp32
#define OFF_TAB 4160     // 50000 x 60 f16 (PRESCALED: zr cols x -log2e, h cols x 2log2e)

__device__ __forceinline__ float ldf(const void* p, int i, int isf) {
  return isf ? ((const float*)p)[i]
             : __bfloat162float(((const __hip_bfloat16*)p)[i]);
}
__device__ __forceinline__ short f2bf(float f) {   // RNE fp32->bf16 bits
  unsigned u = __float_as_uint(f);
  u += 0x7fffu + ((u >> 16) & 1u);
  return (short)(u >> 16);
}
__device__ __forceinline__ float rdl(float v, int l) {
  return __uint_as_float(__builtin_amdgcn_readlane(__float_as_uint(v), l));
}
__device__ __forceinline__ int detect_isf(const void* emb) {
  uint4 dv = ((const uint4*)emb)[threadIdx.x & 63];
  int big = 0;
#pragma unroll
  for (int i = 0; i < 4; ++i) {
    unsigned w = ((const unsigned*)&dv)[i];
    big |= (((w >> 7) & 0xFF) >= 140) | (((w >> 23) & 0xFF) >= 140);
  }
  return (__ballot(big) != 0ull) ? 1 : 0;
}
// gate scale: zr cols (0-39) -log2e, h cols (40-59) +2log2e (folded; see r24).
__device__ __forceinline__ float gsc(int col) {
  return (col < 40) ? -1.44269504f : 2.88539008f;
}

// tab = (emb @ W1 + bi1) * gsc, stored f16 (round-13 MFMA structure, verified).
__global__ __launch_bounds__(256) void build_table(
    const void* __restrict__ emb, const void* __restrict__ W1,
    const void* __restrict__ b1,
    const void* __restrict__ U1, const void* __restrict__ W2,
    const void* __restrict__ U2, const void* __restrict__ b2,
    const void* __restrict__ Wd, const void* __restrict__ bd,
    float* __restrict__ ws)
{
  const int isf = detect_isf(emb);
  if (blockIdx.x == 0) {                     // fold: weight prep
    const int t = threadIdx.x;
    unsigned* wsu = (unsigned*)ws;
    for (int i = t; i < 600; i += 256) {
      const int j = i / 10, p = i % 10;
      const int k0 = 2 * p, k1 = 2 * p + 1;
      const float s = gsc(j);
#define PK(M) ((unsigned)__half_as_ushort(__float2half_rn(ldf(M, k0 * 60 + j, isf) * s)) | \
               ((unsigned)__half_as_ushort(__float2half_rn(ldf(M, k1 * 60 + j, isf) * s)) << 16))
      wsu[OFF_U1P + i] = PK(U1);
      wsu[OFF_W2P + i] = PK(W2);
      wsu[OFF_U2P + i] = PK(U2);
#undef PK
    }
    for (int i = t; i < 120; i += 256) {
      ws[OFF_B1 + i] = ldf(b1, i, isf) * (i >= 60 ? gsc(i - 60) : 1.f);
      ws[OFF_B2 + i] = ldf(b2, i, isf) * gsc(i % 60);
    }
    for (int i = t; i < 300; i += 256) ws[OFF_WD + i] = ldf(Wd, i, isf);
    for (int i = t; i < 15;  i += 256) ws[OFF_BD + i] = ldf(bd, i, isf);
  }

  const int L = threadIdx.x & 63, q = L >> 4, c = L & 15;
  const int wid = blockIdx.x * 4 + (threadIdx.x >> 6);
  unsigned short* __restrict__ tab16 = (unsigned short*)(ws + OFF_TAB);

  __shared__ int4 sB[64][8];
  if (threadIdx.x < 64) {
#pragma unroll
    for (int nt = 0; nt < 4; ++nt) {
      const int col = nt * 16 + c;
      sh8 B0, B1;
#pragma unroll
      for (int jj = 0; jj < 8; ++jj) {
        const int k0 = q * 8 + jj, k1 = 32 + q * 8 + jj;
        B0[jj] = (col < TABW) ? f2bf(ldf(W1, k0 * TABW + col, isf)) : (short)0;
        B1[jj] = (col < TABW && k1 < EMB_D)
                     ? f2bf(ldf(W1, k1 * TABW + col, isf)) : (short)0;
      }
      sB[L][nt * 2]     = *(const int4*)&B0;
      sB[L][nt * 2 + 1] = *(const int4*)&B1;
    }
  }
  float bi[4];
#pragma unroll
  for (int nt = 0; nt < 4; ++nt) {
    const int col = nt * 16 + c;
    bi[nt] = (col < TABW) ? ldf(b1, col, isf) : 0.f;
  }
  __syncthreads();

  for (int tile = wid; tile < NTILE; tile += BBLK * 4) {
    const int v0 = tile * 16;
    sh8 A0, A1;
#pragma unroll
    for (int jj = 0; jj < 8; ++jj) { A0[jj] = 0; A1[jj] = 0; }
    if (!isf) {
      const unsigned short* eb = (const unsigned short*)emb;
      const size_t rb = (size_t)(v0 + c) * EMB_D;
#pragma unroll
      for (int i = 0; i < 4; ++i) {
        unsigned d = *(const unsigned*)(eb + rb + q * 8 + 2 * i);
        A0[2 * i] = (short)(d & 0xffff); A0[2 * i + 1] = (short)(d >> 16);
      }
      const int k1b = 32 + q * 8;
#pragma unroll
      for (int i = 0; i < 4; ++i) {
        const int k = k1b + 2 * i;
        if (k + 1 < EMB_D) {
          unsigned d = *(const unsigned*)(eb + rb + k);
          A1[2 * i] = (short)(d & 0xffff); A1[2 * i + 1] = (short)(d >> 16);
        }
      }
    } else {
      const float* ef = (const float*)emb;
      const size_t rb = (size_t)(v0 + c) * EMB_D;
#pragma unroll
      for (int jj = 0; jj < 8; ++jj) {
        const int k0 = q * 8 + jj, k1 = 32 + q * 8 + jj;
        A0[jj] = f2bf(ef[rb + k0]);
        A1[jj] = (k1 < EMB_D) ? f2bf(ef[rb + k1]) : (short)0;
      }
    }
#pragma unroll
    for (int nt = 0; nt < 4; ++nt) {
      int4 b0i = sB[L][nt * 2], b1i = sB[L][nt * 2 + 1];
      sh8 B0 = *(const sh8*)&b0i, B1 = *(const sh8*)&b1i;
      const int col = nt * 16 + c;
      f4 acc = { bi[nt], bi[nt], bi[nt], bi[nt] };
      acc = __builtin_amdgcn_mfma_f32_16x16x32_bf16(A0, B0, acc, 0, 0, 0);
      acc = __builtin_amdgcn_mfma_f32_16x16x32_bf16(A1, B1, acc, 0, 0, 0);
      if (col < TABW) {
        const float s = gsc(col);
#pragma unroll
        for (int r = 0; r < 4; ++r)
          tab16[(size_t)(v0 + q * 4 + r) * TABW + col] =
              __half_as_ushort(__float2half_rn(acc[r] * s));
      }
    }
  }
}

// ROUND-25: TWO independent GRU streams per wave (elems A=e, B=e+1),
// instruction-pairwise interleaved. Model (r14-r24 data): wall =
// (work-waves/resident) x per-wave CHAIN (~1250cyc/step, ~10cyc/instr;
// SIMD issue only ~33% busy; occupancy pinned ~14-18/CU regardless of
// VGPR). VALU count is at its floor (~56/elem-step); occupancy is a dead
// lever. Remaining lever: fill each wave's stall slots with an INDEPENDENT
// chain. B's instrs hide A's dep/trans/DS latency (6 dot chains, 4-wide
// trans batches -> hazard gaps closed structurally, no s_nops needed).
// Weights shared (v10-39); state/temps duplicated (~100 explicit VGPR,
// cap 128 via (256,4) -> residency unchanged). Waves halve: 4096 total.
// Per-element instruction sequence identical to r24 -> absmax unchanged.
__global__ __launch_bounds__(256, 4) void gru_main(
    const int* __restrict__ x, const float* __restrict__ ws,
    const void* __restrict__ emb, void* __restrict__ out)
{
  const int isf = detect_isf(emb);   // output dtype only
  const int j = threadIdx.x & 63;
  const int e = __builtin_amdgcn_readfirstlane(blockIdx.x * 8 + (threadIdx.x >> 6) * 2);
  const int jc = j < TABW ? j : 0;

  const int* xr = x + (size_t)e * SEQ_T;     // elem B rows at +400 B
  const unsigned short* tab = (const unsigned short*)(ws + OFF_TAB);
  const int o1 = jc * 40;                    // 10 packed dwords per column
  const int jc2 = jc * 2;                    // byte offset in f16 tab row
  const int a1 = ((j - 20) & 63) * 4;        // bpermute addr: r -> h-lanes
  const int a2 = ((j + 40) & 63) * 4;        // bpermute addr: hc -> z-lanes
  const float br1 = ws[OFF_B1 + 60 + jc];    // prescaled
  const float bi2 = ws[OFF_B2 + jc];         // prescaled
  const float br2 = ws[OFF_B2 + 60 + jc];    // prescaled

  // per-wave LDS: 512 B = elem A 256 B (h1 @0, h2 @128) + elem B 256 B.
  __shared__ char sbuf[2048];
  const unsigned lb = (unsigned)(uintptr_t)&sbuf[0] + (threadIdx.x >> 6) * 512;
  const int lmap = (j < 20 ? 2 * j : 40 + 2 * (j - 20));
  const int wadA = (int)(lb + lmap),       radA = (int)lb;
  const int wadB = (int)(lb + 256 + lmap), radB = (int)(lb + 256);
  float h2oA, h2oB;

  asm volatile(
    // ---- shared packed f16 weights: U1P v10-19, W2P v20-29, U2P v30-39 --
    "global_load_dwordx4 v[10:13], %[o1], %[wsp] offset:0\n\t"
    "global_load_dwordx4 v[14:17], %[o1], %[wsp] offset:16\n\t"
    "global_load_dwordx2 v[18:19], %[o1], %[wsp] offset:32\n\t"
    "v_add_u32 v98, 0x960, %[o1]\n\t"
    "v_add_u32 v109, 0x12c0, %[o1]\n\t"
    "global_load_dwordx4 v[20:23], v98, %[wsp] offset:0\n\t"
    "global_load_dwordx4 v[24:27], v98, %[wsp] offset:16\n\t"
    "global_load_dwordx2 v[28:29], v98, %[wsp] offset:32\n\t"
    "global_load_dwordx4 v[30:33], v109, %[wsp] offset:0\n\t"
    "global_load_dwordx4 v[34:37], v109, %[wsp] offset:16\n\t"
    "global_load_dwordx2 v[38:39], v109, %[wsp] offset:32\n\t"
    // ---- zero: masters v80-83; h2 pairs A v50-59, B v70-79 ----
    "v_mov_b32 v80, 0\n\tv_mov_b32 v81, 0\n\t"
    "v_mov_b32 v82, 0\n\tv_mov_b32 v83, 0\n\t"
    "v_mov_b32 v50, 0\n\tv_mov_b32 v51, 0\n\t"
    "v_mov_b32 v52, 0\n\tv_mov_b32 v53, 0\n\t"
    "v_mov_b32 v54, 0\n\tv_mov_b32 v55, 0\n\t"
    "v_mov_b32 v56, 0\n\tv_mov_b32 v57, 0\n\t"
    "v_mov_b32 v58, 0\n\tv_mov_b32 v59, 0\n\t"
    "v_mov_b32 v70, 0\n\tv_mov_b32 v71, 0\n\t"
    "v_mov_b32 v72, 0\n\tv_mov_b32 v73, 0\n\t"
    "v_mov_b32 v74, 0\n\tv_mov_b32 v75, 0\n\t"
    "v_mov_b32 v76, 0\n\tv_mov_b32 v77, 0\n\t"
    "v_mov_b32 v78, 0\n\tv_mov_b32 v79, 0\n\t"
    // ---- prime idx + mx: A0->v97 B0->v108 A1->v84 B1->v86 A2->v85 B2->v87
    "s_load_dword s65, %[xp], 0x0\n\t"
    "s_load_dword s66, %[xp], 0x4\n\t"
    "s_load_dword s68, %[xp], 0x8\n\t"
    "s_load_dword s71, %[xp], 0x190\n\t"
    "s_load_dword s72, %[xp], 0x194\n\t"
    "s_load_dword s73, %[xp], 0x198\n\t"
    "s_waitcnt lgkmcnt(0)\n\t"
    "s_mul_i32 s65, s65, 120\n\t"
    "s_mul_i32 s66, s66, 120\n\t"
    "s_mul_i32 s68, s68, 120\n\t"
    "s_mul_i32 s71, s71, 120\n\t"
    "s_mul_i32 s72, s72, 120\n\t"
    "s_mul_i32 s73, s73, 120\n\t"
    "v_add_u32 v98, s65, %[jc2]\n\t"
    "global_load_ushort v97, v98, %[tabp]\n\t"
    "v_add_u32 v98, s71, %[jc2]\n\t"
    "global_load_ushort v108, v98, %[tabp]\n\t"
    "v_add_u32 v98, s66, %[jc2]\n\t"
    "global_load_ushort v84, v98, %[tabp]\n\t"
    "v_add_u32 v98, s72, %[jc2]\n\t"
    "global_load_ushort v86, v98, %[tabp]\n\t"
    "v_add_u32 v98, s68, %[jc2]\n\t"
    "global_load_ushort v85, v98, %[tabp]\n\t"
    "v_add_u32 v98, s73, %[jc2]\n\t"
    "global_load_ushort v87, v98, %[tabp]\n\t"
    "s_load_dword s65, %[xp], 0xc\n\t"     // A idx3 (odd)
    "s_load_dword s68, %[xp], 0x10\n\t"    // A idx4 (even)
    "s_load_dword s71, %[xp], 0x19c\n\t"   // B idx3 (odd)
    "s_load_dword s73, %[xp], 0x1a0\n\t"   // B idx4 (even)
    "s_movk_i32 s64, 0x14\n\t"             // A odd next-offset
    "s_movk_i32 s69, 0x18\n\t"             // A even next-offset
    "s_movk_i32 s70, 0x1a4\n\t"            // B odd next-offset
    "s_movk_i32 s72, 0x1a8\n\t"            // B even next-offset
    "s_movk_i32 s67, 0x32\n\t"             // 50 iterations
    "s_waitcnt vmcnt(4)\n\t"               // weights + mxA0,mxB0 ready
    // ======== PROLOGUE: L1(0) for A and B (h=0 -> mh = br1) ========
    "v_cvt_f32_f16 v97, v97\n\t"
    "v_cvt_f32_f16 v108, v108\n\t"
    "v_mov_b32 v88, %[br1]\n\t"
    "v_mov_b32 v99, %[br1]\n\t"
    "v_add_f32 v91, v97, v88\n\t"
    "v_add_f32 v102, v108, v99\n\t"
    "v_exp_f32 v91, v91\n\t"
    "v_exp_f32 v102, v102\n\t"
    "s_nop 1\n\t"
    "v_add_f32 v91, 1.0, v91\n\t"
    "v_add_f32 v102, 1.0, v102\n\t"
    "v_rcp_f32 v91, v91\n\t"
    "v_rcp_f32 v102, v102\n\t"
    "s_nop 1\n\t"
    "ds_bpermute_b32 v93, %[a1], v91\n\t"
    "ds_bpermute_b32 v104, %[a1], v102\n\t"
    "s_waitcnt lgkmcnt(0)\n\t"
    "v_fma_f32 v95, v93, v88, v97\n\t"
    "v_fma_f32 v106, v104, v99, v108\n\t"
    "v_exp_f32 v95, v95\n\t"
    "v_exp_f32 v106, v106\n\t"
    "s_nop 1\n\t"
    "v_add_f32 v95, 1.0, v95\n\t"
    "v_add_f32 v106, 1.0, v106\n\t"
    "v_rcp_f32 v95, v95\n\t"
    "v_rcp_f32 v106, v106\n\t"
    "s_nop 1\n\t"
    "v_fma_f32 v95, -2.0, v95, 1.0\n\t"
    "v_fma_f32 v106, -2.0, v106, 1.0\n\t"
    "ds_bpermute_b32 v93, %[a2], v95\n\t"
    "ds_bpermute_b32 v104, %[a2], v106\n\t"
    "s_waitcnt lgkmcnt(0)\n\t"
    "v_sub_f32 v97, v80, v93\n\t"
    "v_fma_f32 v80, v91, v97, v93\n\t"     // h1A(0)
    "v_sub_f32 v108, v82, v104\n\t"
    "v_fma_f32 v82, v102, v108, v104\n\t"  // h1B(0)
    "v_cvt_f16_f32 v93, v80\n\t"
    "v_cvt_f16_f32 v104, v82\n\t"
    "s_nop 1\n\t"
    "ds_write_b16 %[wadA], v93\n\t"
    "ds_write_b16 %[wadB], v104\n\t"
    "ds_read_b128 v[40:43], %[radA]\n\t"
    "ds_read_b128 v[44:47], %[radA] offset:16\n\t"
    "ds_read_b64  v[48:49], %[radA] offset:32\n\t"
    "ds_read_b128 v[60:63], %[radB]\n\t"
    "ds_read_b128 v[64:67], %[radB] offset:16\n\t"
    "ds_read_b64  v[68:69], %[radB] offset:32\n\t"
    // ======== LOOP k=0..49 ========
    "0:\n\t"
    // ---------- HALF ODD: L2(2k)+L1(2k+1) for A and B. mx: v84/v86 ------
    "s_waitcnt lgkmcnt(0)\n\t"
    "v_dot2_f32_f16 v88, v40, v10, %[br1]\n\t"
    "v_dot2_f32_f16 v89, v40, v20, %[bi2]\n\t"
    "v_dot2_f32_f16 v90, v50, v30, %[br2]\n\t"
    "v_dot2_f32_f16 v99, v60, v10, %[br1]\n\t"
    "v_dot2_f32_f16 v100, v60, v20, %[bi2]\n\t"
    "v_dot2_f32_f16 v101, v70, v30, %[br2]\n\t"
    "v_dot2_f32_f16 v88, v41, v11, v88\n\t"
    "v_dot2_f32_f16 v89, v41, v21, v89\n\t"
    "v_dot2_f32_f16 v90, v51, v31, v90\n\t"
    "v_dot2_f32_f16 v99, v61, v11, v99\n\t"
    "v_dot2_f32_f16 v100, v61, v21, v100\n\t"
    "v_dot2_f32_f16 v101, v71, v31, v101\n\t"
    "v_dot2_f32_f16 v88, v42, v12, v88\n\t"
    "v_dot2_f32_f16 v89, v42, v22, v89\n\t"
    "v_dot2_f32_f16 v90, v52, v32, v90\n\t"
    "v_dot2_f32_f16 v99, v62, v12, v99\n\t"
    "v_dot2_f32_f16 v100, v62, v22, v100\n\t"
    "v_dot2_f32_f16 v101, v72, v32, v101\n\t"
    "v_dot2_f32_f16 v88, v43, v13, v88\n\t"
    "v_dot2_f32_f16 v89, v43, v23, v89\n\t"
    "v_dot2_f32_f16 v90, v53, v33, v90\n\t"
    "v_dot2_f32_f16 v99, v63, v13, v99\n\t"
    "v_dot2_f32_f16 v100, v63, v23, v100\n\t"
    "v_dot2_f32_f16 v101, v73, v33, v101\n\t"
    "v_dot2_f32_f16 v88, v44, v14, v88\n\t"
    "v_dot2_f32_f16 v89, v44, v24, v89\n\t"
    "v_dot2_f32_f16 v90, v54, v34, v90\n\t"
    "v_dot2_f32_f16 v99, v64, v14, v99\n\t"
    "v_dot2_f32_f16 v100, v64, v24, v100\n\t"
    "v_dot2_f32_f16 v101, v74, v34, v101\n\t"
    "v_dot2_f32_f16 v88, v45, v15, v88\n\t"
    "v_dot2_f32_f16 v89, v45, v25, v89\n\t"
    "v_dot2_f32_f16 v90, v55, v35, v90\n\t"
    "v_dot2_f32_f16 v99, v65, v15, v99\n\t"
    "v_dot2_f32_f16 v100, v65, v25, v100\n\t"
    "v_dot2_f32_f16 v101, v75, v35, v101\n\t"
    "v_dot2_f32_f16 v88, v46, v16, v88\n\t"
    "v_dot2_f32_f16 v89, v46, v26, v89\n\t"
    "v_dot2_f32_f16 v90, v56, v36, v90\n\t"
    "v_dot2_f32_f16 v99, v66, v16, v99\n\t"
    "v_dot2_f32_f16 v100, v66, v26, v100\n\t"
    "v_dot2_f32_f16 v101, v76, v36, v101\n\t"
    "v_dot2_f32_f16 v88, v47, v17, v88\n\t"
    "v_dot2_f32_f16 v89, v47, v27, v89\n\t"
    "v_dot2_f32_f16 v90, v57, v37, v90\n\t"
    "v_dot2_f32_f16 v99, v67, v17, v99\n\t"
    "v_dot2_f32_f16 v100, v67, v27, v100\n\t"
    "v_dot2_f32_f16 v101, v77, v37, v101\n\t"
    "v_dot2_f32_f16 v88, v48, v18, v88\n\t"
    "v_dot2_f32_f16 v89, v48, v28, v89\n\t"
    "v_dot2_f32_f16 v90, v58, v38, v90\n\t"
    "v_dot2_f32_f16 v99, v68, v18, v99\n\t"
    "v_dot2_f32_f16 v100, v68, v28, v100\n\t"
    "v_dot2_f32_f16 v101, v78, v38, v101\n\t"
    "v_dot2_f32_f16 v88, v49, v19, v88\n\t"
    "v_dot2_f32_f16 v89, v49, v29, v89\n\t"
    "v_dot2_f32_f16 v90, v59, v39, v90\n\t"
    "v_dot2_f32_f16 v99, v69, v19, v99\n\t"
    "v_dot2_f32_f16 v100, v69, v29, v100\n\t"
    "v_dot2_f32_f16 v101, v79, v39, v101\n\t"
    "s_waitcnt vmcnt(2)\n\t"               // mxA/mxB (odd) ready
    "v_cvt_f32_f16 v84, v84\n\t"
    "v_cvt_f32_f16 v86, v86\n\t"
    "s_nop 1\n\t"
    "v_add_f32 v91, v84, v88\n\t"
    "v_add_f32 v92, v89, v90\n\t"
    "v_add_f32 v102, v86, v99\n\t"
    "v_add_f32 v103, v100, v101\n\t"
    "v_exp_f32 v91, v91\n\t"
    "v_exp_f32 v92, v92\n\t"
    "v_exp_f32 v102, v102\n\t"
    "v_exp_f32 v103, v103\n\t"
    "v_add_f32 v91, 1.0, v91\n\t"
    "v_add_f32 v92, 1.0, v92\n\t"
    "v_add_f32 v102, 1.0, v102\n\t"
    "v_add_f32 v103, 1.0, v103\n\t"
    "v_rcp_f32 v91, v91\n\t"
    "v_rcp_f32 v92, v92\n\t"
    "v_rcp_f32 v102, v102\n\t"
    "v_rcp_f32 v103, v103\n\t"
    "ds_bpermute_b32 v93, %[a1], v91\n\t"
    "ds_bpermute_b32 v94, %[a1], v92\n\t"
    "ds_bpermute_b32 v104, %[a1], v102\n\t"
    "ds_bpermute_b32 v105, %[a1], v103\n\t"
    "s_waitcnt lgkmcnt(0)\n\t"
    "v_fma_f32 v95, v93, v88, v84\n\t"     // hp1A (last v84 use)
    "v_fma_f32 v96, v94, v90, v89\n\t"     // hp2A
    "v_fma_f32 v106, v104, v99, v86\n\t"   // hp1B (last v86 use)
    "v_fma_f32 v107, v105, v101, v100\n\t" // hp2B
    // prefetch mx(2k+3) + idx(2k+5) for A and B
    "s_mul_i32 s66, s65, 120\n\t"
    "v_add_u32 v98, s66, %[jc2]\n\t"
    "global_load_ushort v84, v98, %[tabp]\n\t"
    "s_min_u32 s64, s64, 0x18c\n\t"
    "s_load_dword s65, %[xp], s64\n\t"
    "s_add_u32 s64, s64, 8\n\t"
    "s_mul_i32 s66, s71, 120\n\t"
    "v_add_u32 v109, s66, %[jc2]\n\t"
    "global_load_ushort v86, v109, %[tabp]\n\t"
    "s_min_u32 s70, s70, 0x31c\n\t"
    "s_load_dword s71, %[xp], s70\n\t"
    "s_add_u32 s70, s70, 8\n\t"
    // tanh
    "v_exp_f32 v95, v95\n\t"
    "v_exp_f32 v96, v96\n\t"
    "v_exp_f32 v106, v106\n\t"
    "v_exp_f32 v107, v107\n\t"
    "v_add_f32 v95, 1.0, v95\n\t"
    "v_add_f32 v96, 1.0, v96\n\t"
    "v_add_f32 v106, 1.0, v106\n\t"
    "v_add_f32 v107, 1.0, v107\n\t"
    "v_rcp_f32 v95, v95\n\t"
    "v_rcp_f32 v96, v96\n\t"
    "v_rcp_f32 v106, v106\n\t"
    "v_rcp_f32 v107, v107\n\t"
    "v_fma_f32 v95, -2.0, v95, 1.0\n\t"
    "v_fma_f32 v96, -2.0, v96, 1.0\n\t"
    "v_fma_f32 v106, -2.0, v106, 1.0\n\t"
    "v_fma_f32 v107, -2.0, v107, 1.0\n\t"
    "ds_bpermute_b32 v93, %[a2], v95\n\t"
    "ds_bpermute_b32 v94, %[a2], v96\n\t"
    "ds_bpermute_b32 v104, %[a2], v106\n\t"
    "ds_bpermute_b32 v105, %[a2], v107\n\t"
    "s_waitcnt lgkmcnt(0)\n\t"
    "v_sub_f32 v97, v80, v93\n\t"
    "v_fma_f32 v80, v91, v97, v93\n\t"     // h1A(2k+1)
    "v_sub_f32 v97, v81, v94\n\t"
    "v_fma_f32 v81, v92, v97, v94\n\t"     // h2A(2k)
    "v_sub_f32 v108, v82, v104\n\t"
    "v_fma_f32 v82, v102, v108, v104\n\t"  // h1B(2k+1)
    "v_sub_f32 v108, v83, v105\n\t"
    "v_fma_f32 v83, v103, v108, v105\n\t"  // h2B(2k)
    "v_cvt_f16_f32 v93, v80\n\t"
    "v_cvt_f16_f32 v94, v81\n\t"
    "v_cvt_f16_f32 v104, v82\n\t"
    "v_cvt_f16_f32 v105, v83\n\t"
    "ds_write_b16 %[wadA], v93\n\t"
    "ds_write_b16 %[wadA], v94 offset:128\n\t"
    "ds_write_b16 %[wadB], v104\n\t"
    "ds_write_b16 %[wadB], v105 offset:128\n\t"
    "ds_read_b128 v[40:43], %[radA]\n\t"
    "ds_read_b128 v[44:47], %[radA] offset:16\n\t"
    "ds_read_b64  v[48:49], %[radA] offset:32\n\t"
    "ds_read_b128 v[50:53], %[radA] offset:128\n\t"
    "ds_read_b128 v[54:57], %[radA] offset:144\n\t"
    "ds_read_b64  v[58:59], %[radA] offset:160\n\t"
    "ds_read_b128 v[60:63], %[radB]\n\t"
    "ds_read_b128 v[64:67], %[radB] offset:16\n\t"
    "ds_read_b64  v[68:69], %[radB] offset:32\n\t"
    "ds_read_b128 v[70:73], %[radB] offset:128\n\t"
    "ds_read_b128 v[74:77], %[radB] offset:144\n\t"
    "ds_read_b64  v[78:79], %[radB] offset:160\n\t"
    // ---------- HALF EVEN: L2(2k+1)+L1(2k+2). mx: v85/v87 ----------
    "s_waitcnt lgkmcnt(0)\n\t"
    "v_dot2_f32_f16 v88, v40, v10, %[br1]\n\t"
    "v_dot2_f32_f16 v89, v40, v20, %[bi2]\n\t"
    "v_dot2_f32_f16 v90, v50, v30, %[br2]\n\t"
    "v_dot2_f32_f16 v99, v60, v10, %[br1]\n\t"
    "v_dot2_f32_f16 v100, v60, v20, %[bi2]\n\t"
    "v_dot2_f32_f16 v101, v70, v30, %[br2]\n\t"
    "v_dot2_f32_f16 v88, v41, v11, v88\n\t"
    "v_dot2_f32_f16 v89, v41, v21, v89\n\t"
    "v_dot2_f32_f16 v90, v51, v31, v90\n\t"
    "v_dot2_f32_f16 v99, v61, v11, v99\n\t"
    "v_dot2_f32_f16 v100, v61, v21, v100\n\t"
    "v_dot2_f32_f16 v101, v71, v31, v101\n\t"
    "v_dot2_f32_f16 v88, v42, v12, v88\n\t"
    "v_dot2_f32_f16 v89, v42, v22, v89\n\t"
    "v_dot2_f32_f16 v90, v52, v32, v90\n\t"
    "v_dot2_f32_f16 v99, v62, v12, v99\n\t"
    "v_dot2_f32_f16 v100, v62, v22, v100\n\t"
    "v_dot2_f32_f16 v101, v72, v32, v101\n\t"
    "v_dot2_f32_f16 v88, v43, v13, v88\n\t"
    "v_dot2_f32_f16 v89, v43, v23, v89\n\t"
    "v_dot2_f32_f16 v90, v53, v33, v90\n\t"
    "v_dot2_f32_f16 v99, v63, v13, v99\n\t"
    "v_dot2_f32_f16 v100, v63, v23, v100\n\t"
    "v_dot2_f32_f16 v101, v73, v33, v101\n\t"
    "v_dot2_f32_f16 v88, v44, v14, v88\n\t"
    "v_dot2_f32_f16 v89, v44, v24, v89\n\t"
    "v_dot2_f32_f16 v90, v54, v34, v90\n\t"
    "v_dot2_f32_f16 v99, v64, v14, v99\n\t"
    "v_dot2_f32_f16 v100, v64, v24, v100\n\t"
    "v_dot2_f32_f16 v101, v74, v34, v101\n\t"
    "v_dot2_f32_f16 v88, v45, v15, v88\n\t"
    "v_dot2_f32_f16 v89, v45, v25, v89\n\t"
    "v_dot2_f32_f16 v90, v55, v35, v90\n\t"
    "v_dot2_f32_f16 v99, v65, v15, v99\n\t"
    "v_dot2_f32_f16 v100, v65, v25, v100\n\t"
    "v_dot2_f32_f16 v101, v75, v35, v101\n\t"
    "v_dot2_f32_f16 v88, v46, v16, v88\n\t"
    "v_dot2_f32_f16 v89, v46, v26, v89\n\t"
    "v_dot2_f32_f16 v90, v56, v36, v90\n\t"
    "v_dot2_f32_f16 v99, v66, v16, v99\n\t"
    "v_dot2_f32_f16 v100, v66, v26, v100\n\t"
    "v_dot2_f32_f16 v101, v76, v36, v101\n\t"
    "v_dot2_f32_f16 v88, v47, v17, v88\n\t"
    "v_dot2_f32_f16 v89, v47, v27, v89\n\t"
    "v_dot2_f32_f16 v90, v57, v37, v90\n\t"
    "v_dot2_f32_f16 v99, v67, v17, v99\n\t"
    "v_dot2_f32_f16 v100, v67, v27, v100\n\t"
    "v_dot2_f32_f16 v101, v77, v37, v101\n\t"
    "v_dot2_f32_f16 v88, v48, v18, v88\n\t"
    "v_dot2_f32_f16 v89, v48, v28, v89\n\t"
    "v_dot2_f32_f16 v90, v58, v38, v90\n\t"
    "v_dot2_f32_f16 v99, v68, v18, v99\n\t"
    "v_dot2_f32_f16 v100, v68, v28, v100\n\t"
    "v_dot2_f32_f16 v101, v78, v38, v101\n\t"
    "v_dot2_f32_f16 v88, v49, v19, v88\n\t"
    "v_dot2_f32_f16 v89, v49, v29, v89\n\t"
    "v_dot2_f32_f16 v90, v59, v39, v90\n\t"
    "v_dot2_f32_f16 v99, v69, v19, v99\n\t"
    "v_dot2_f32_f16 v100, v69, v29, v100\n\t"
    "v_dot2_f32_f16 v101, v79, v39, v101\n\t"
    "s_waitcnt vmcnt(2)\n\t"               // mxA/mxB (even) ready
    "v_cvt_f32_f16 v85, v85\n\t"
    "v_cvt_f32_f16 v87, v87\n\t"
    "s_nop 1\n\t"
    "v_add_f32 v91, v85, v88\n\t"
    "v_add_f32 v92, v89, v90\n\t"
    "v_add_f32 v102, v87, v99\n\t"
    "v_add_f32 v103, v100, v101\n\t"
    "v_exp_f32 v91, v91\n\t"
    "v_exp_f32 v92, v92\n\t"
    "v_exp_f32 v102, v102\n\t"
    "v_exp_f32 v103, v103\n\t"
    "v_add_f32 v91, 1.0, v91\n\t"
    "v_add_f32 v92, 1.0, v92\n\t"
    "v_add_f32 v102, 1.0, v102\n\t"
    "v_add_f32 v103, 1.0, v103\n\t"
    "v_rcp_f32 v91, v91\n\t"
    "v_rcp_f32 v92, v92\n\t"
    "v_rcp_f32 v102, v102\n\t"
    "v_rcp_f32 v103, v103\n\t"
    "ds_bpermute_b32 v93, %[a1], v91\n\t"
    "ds_bpermute_b32 v94, %[a1], v92\n\t"
    "ds_bpermute_b32 v104, %[a1], v102\n\t"
    "ds_bpermute_b32 v105, %[a1], v103\n\t"
    "s_waitcnt lgkmcnt(0)\n\t"
    "v_fma_f32 v95, v93, v88, v85\n\t"
    "v_fma_f32 v96, v94, v90, v89\n\t"
    "v_fma_f32 v106, v104, v99, v87\n\t"
    "v_fma_f32 v107, v105, v101, v100\n\t"
    // prefetch mx(2k+4) + idx(2k+6)
    "s_mul_i32 s66, s68, 120\n\t"
    "v_add_u32 v98, s66, %[jc2]\n\t"
    "global_load_ushort v85, v98, %[tabp]\n\t"
    "s_min_u32 s69, s69, 0x188\n\t"
    "s_load_dword s68, %[xp], s69\n\t"
    "s_add_u32 s69, s69, 8\n\t"
    "s_mul_i32 s66, s73, 120\n\t"
    "v_add_u32 v109, s66, %[jc2]\n\t"
    "global_load_ushort v87, v109, %[tabp]\n\t"
    "s_min_u32 s72, s72, 0x318\n\t"
    "s_load_dword s73, %[xp], s72\n\t"
    "s_add_u32 s72, s72, 8\n\t"
    // tanh
    "v_exp_f32 v95, v95\n\t"
    "v_exp_f32 v96, v96\n\t"
    "v_exp_f32 v106, v106\n\t"
    "v_exp_f32 v107, v107\n\t"
    "v_add_f32 v95, 1.0, v95\n\t"
    "v_add_f32 v96, 1.0, v96\n\t"
    "v_add_f32 v106, 1.0, v106\n\t"
    "v_add_f32 v107, 1.0, v107\n\t"
    "v_rcp_f32 v95, v95\n\t"
    "v_rcp_f32 v96, v96\n\t"
    "v_rcp_f32 v106, v106\n\t"
    "v_rcp_f32 v107, v107\n\t"
    "v_fma_f32 v95, -2.0, v95, 1.0\n\t"
    "v_fma_f32 v96, -2.0, v96, 1.0\n\t"
    "v_fma_f32 v106, -2.0, v106, 1.0\n\t"
    "v_fma_f32 v107, -2.0, v107, 1.0\n\t"
    "ds_bpermute_b32 v93, %[a2], v95\n\t"
    "ds_bpermute_b32 v94, %[a2], v96\n\t"
    "ds_bpermute_b32 v104, %[a2], v106\n\t"
    "ds_bpermute_b32 v105, %[a2], v107\n\t"
    "s_waitcnt lgkmcnt(0)\n\t"
    "v_sub_f32 v97, v80, v93\n\t"
    "v_fma_f32 v80, v91, v97, v93\n\t"     // h1A(2k+2)
    "v_sub_f32 v97, v81, v94\n\t"
    "v_fma_f32 v81, v92, v97, v94\n\t"     // h2A(2k+1)
    "v_sub_f32 v108, v82, v104\n\t"
    "v_fma_f32 v82, v102, v108, v104\n\t"  // h1B(2k+2)
    "v_sub_f32 v108, v83, v105\n\t"
    "v_fma_f32 v83, v103, v108, v105\n\t"  // h2B(2k+1)
    "v_cvt_f16_f32 v93, v80\n\t"
    "v_cvt_f16_f32 v94, v81\n\t"
    "v_cvt_f16_f32 v104, v82\n\t"
    "v_cvt_f16_f32 v105, v83\n\t"
    "ds_write_b16 %[wadA], v93\n\t"
    "ds_write_b16 %[wadA], v94 offset:128\n\t"
    "ds_write_b16 %[wadB], v104\n\t"
    "ds_write_b16 %[wadB], v105 offset:128\n\t"
    "ds_read_b128 v[40:43], %[radA]\n\t"
    "ds_read_b128 v[44:47], %[radA] offset:16\n\t"
    "ds_read_b64  v[48:49], %[radA] offset:32\n\t"
    "ds_read_b128 v[50:53], %[radA] offset:128\n\t"
    "ds_read_b128 v[54:57], %[radA] offset:144\n\t"
    "ds_read_b64  v[58:59], %[radA] offset:160\n\t"
    "ds_read_b128 v[60:63], %[radB]\n\t"
    "ds_read_b128 v[64:67], %[radB] offset:16\n\t"
    "ds_read_b64  v[68:69], %[radB] offset:32\n\t"
    "ds_read_b128 v[70:73], %[radB] offset:128\n\t"
    "ds_read_b128 v[74:77], %[radB] offset:144\n\t"
    "ds_read_b64  v[78:79], %[radB] offset:160\n\t"
    "s_sub_u32 s67, s67, 1\n\t"
    "s_cmp_lg_u32 s67, 0\n\t"
    "s_cbranch_scc1 0b\n\t"
    "s_waitcnt vmcnt(0) lgkmcnt(0)\n\t"
    "v_mov_b32 %[hA], v81\n\t"
    "v_mov_b32 %[hB], v83\n\t"
    : [hA] "=v"(h2oA), [hB] "=v"(h2oB)
    : [wsp] "s"(ws), [xp] "s"(xr), [tabp] "s"(tab),
      [o1] "v"(o1), [jc2] "v"(jc2), [a1] "v"(a1), [a2] "v"(a2),
      [br1] "v"(br1), [bi2] "v"(bi2), [br2] "v"(br2),
      [wadA] "v"(wadA), [radA] "v"(radA), [wadB] "v"(wadB), [radB] "v"(radB)
    : "memory", "vcc", "scc",
      "v10","v11","v12","v13","v14","v15","v16","v17","v18","v19",
      "v20","v21","v22","v23","v24","v25","v26","v27","v28","v29",
      "v30","v31","v32","v33","v34","v35","v36","v37","v38","v39",
      "v40","v41","v42","v43","v44","v45","v46","v47","v48","v49",
      "v50","v51","v52","v53","v54","v55","v56","v57","v58","v59",
      "v60","v61","v62","v63","v64","v65","v66","v67","v68","v69",
      "v70","v71","v72","v73","v74","v75","v76","v77","v78","v79",
      "v80","v81","v82","v83","v84","v85","v86","v87","v88","v89",
      "v90","v91","v92","v93","v94","v95","v96","v97","v98","v99",
      "v100","v101","v102","v103","v104","v105","v106","v107","v108","v109",
      "s64","s65","s66","s67","s68","s69","s70","s71","s72","s73");

  // ---- dense: logits = h2 @ Wd + bd for elems e (A) and e+1 (B) ----
  if (j < 15) {
    float a = ws[OFF_BD + j];
    float b = a;
#pragma unroll
    for (int k = 0; k < HID; ++k) {
      const float w = ws[OFF_WD + k * 15 + j];
      a = fmaf(rdl(h2oA, k), w, a);
      b = fmaf(rdl(h2oB, k), w, b);
    }
    if (isf) {
      ((float*)out)[(size_t)e * 15 + j] = a;
      ((float*)out)[(size_t)(e + 1) * 15 + j] = b;
    } else {
      ((__hip_bfloat16*)out)[(size_t)e * 15 + j] = __float2bfloat16(a);
      ((__hip_bfloat16*)out)[(size_t)(e + 1) * 15 + j] = __float2bfloat16(b);
    }
  }
}

extern "C" void kernel_launch(void* const* d_in, const int* in_sizes, int n_in,
                              void* d_out, int out_size, void* d_ws, size_t ws_size,
                              hipStream_t stream) {
  const int* x    = (const int*)d_in[0];
  const void* emb = d_in[1];
  const void* W1  = d_in[2];
  const void* U1  = d_in[3];
  const void* b1  = d_in[4];
  const void* W2  = d_in[5];
  const void* U2  = d_in[6];
  const void* b2  = d_in[7];
  const void* Wd  = d_in[8];
  const void* bd  = d_in[9];
  float* ws = (float*)d_ws;   // 6.02 MB used (12 MB proven safe)

  build_table<<<BBLK, 256, 0, stream>>>(
      emb, W1, b1, U1, W2, U2, b2, Wd, bd, ws);
  gru_main<<<1024, 256, 0, stream>>>(x, ws, emb, d_out);
}

// Round 12
// 194.267 us; speedup vs baseline: 1.0536x; 1.0536x over previous
//
#include <hip/hip_runtime.h>
#include <hip/hip_bf16.h>
#include <hip/hip_fp16.h>

#define SEQ_T 100
#define HID 20
#define EMB_D 50
#define VOCAB_N 50000
#define TABW 60          // tab row stride = 60 gate cols [z20|r20|h20]
#define NTILE 3125       // VOCAB_N/16
#define BBLK 782         // build_table blocks (x4 waves, 1 tile/wave)

typedef short sh8 __attribute__((ext_vector_type(8)));   // 8 bf16 bit patterns
typedef float f4  __attribute__((ext_vector_type(4)));

// ws layout (float/dword offsets). tab f16: 50000*60*2B = 6 MB.
#define OFF_U1P 0        // 600 dwords (60 cols x 10 packed f16 k-pairs, PRESCALED)
#define OFF_W2P 600
#define OFF_U2P 1200
#define OFF_B1  3600     // 120 fp32 (first 60 raw bi1 for build MFMA; last 60 br1 prescaled)
#define OFF_B2  3720     // 120 fp32 (all prescaled)
#define OFF_WD  3840     // 300 fp32
#define OFF_BD  4140     // 15 fp32
#define OFF_TAB 4160     // 50000 x 60 f16 (PRESCALED: zr cols x -log2e, h cols x 2log2e)

__device__ __forceinline__ float ldf(const void* p, int i, int isf) {
  return isf ? ((const float*)p)[i]
             : __bfloat162float(((const __hip_bfloat16*)p)[i]);
}
__device__ __forceinline__ short f2bf(float f) {   // RNE fp32->bf16 bits
  unsigned u = __float_as_uint(f);
  u += 0x7fffu + ((u >> 16) & 1u);
  return (short)(u >> 16);
}
__device__ __forceinline__ float rdl(float v, int l) {
  return __uint_as_float(__builtin_amdgcn_readlane(__float_as_uint(v), l));
}
__device__ __forceinline__ int detect_isf(const void* emb) {
  uint4 dv = ((const uint4*)emb)[threadIdx.x & 63];
  int big = 0;
#pragma unroll
  for (int i = 0; i < 4; ++i) {
    unsigned w = ((const unsigned*)&dv)[i];
    big |= (((w >> 7) & 0xFF) >= 140) | (((w >> 23) & 0xFF) >= 140);
  }
  return (__ballot(big) != 0ull) ? 1 : 0;
}
// gate scale: zr cols (0-39) -log2e, h cols (40-59) +2log2e (folded; see r24).
__device__ __forceinline__ float gsc(int col) {
  return (col < 40) ? -1.44269504f : 2.88539008f;
}

// tab = (emb @ W1 + bi1) * gsc, stored f16 (round-13 MFMA structure, verified).
__global__ __launch_bounds__(256) void build_table(
    const void* __restrict__ emb, const void* __restrict__ W1,
    const void* __restrict__ b1,
    const void* __restrict__ U1, const void* __restrict__ W2,
    const void* __restrict__ U2, const void* __restrict__ b2,
    const void* __restrict__ Wd, const void* __restrict__ bd,
    float* __restrict__ ws)
{
  const int isf = detect_isf(emb);
  if (blockIdx.x == 0) {                     // fold: weight prep
    const int t = threadIdx.x;
    unsigned* wsu = (unsigned*)ws;
    for (int i = t; i < 600; i += 256) {
      const int j = i / 10, p = i % 10;
      const int k0 = 2 * p, k1 = 2 * p + 1;
      const float s = gsc(j);
#define PK(M) ((unsigned)__half_as_ushort(__float2half_rn(ldf(M, k0 * 60 + j, isf) * s)) | \
               ((unsigned)__half_as_ushort(__float2half_rn(ldf(M, k1 * 60 + j, isf) * s)) << 16))
      wsu[OFF_U1P + i] = PK(U1);
      wsu[OFF_W2P + i] = PK(W2);
      wsu[OFF_U2P + i] = PK(U2);
#undef PK
    }
    for (int i = t; i < 120; i += 256) {
      ws[OFF_B1 + i] = ldf(b1, i, isf) * (i >= 60 ? gsc(i - 60) : 1.f);
      ws[OFF_B2 + i] = ldf(b2, i, isf) * gsc(i % 60);
    }
    for (int i = t; i < 300; i += 256) ws[OFF_WD + i] = ldf(Wd, i, isf);
    for (int i = t; i < 15;  i += 256) ws[OFF_BD + i] = ldf(bd, i, isf);
  }

  const int L = threadIdx.x & 63, q = L >> 4, c = L & 15;
  const int wid = blockIdx.x * 4 + (threadIdx.x >> 6);
  unsigned short* __restrict__ tab16 = (unsigned short*)(ws + OFF_TAB);

  __shared__ int4 sB[64][8];
  if (threadIdx.x < 64) {
#pragma unroll
    for (int nt = 0; nt < 4; ++nt) {
      const int col = nt * 16 + c;
      sh8 B0, B1;
#pragma unroll
      for (int jj = 0; jj < 8; ++jj) {
        const int k0 = q * 8 + jj, k1 = 32 + q * 8 + jj;
        B0[jj] = (col < TABW) ? f2bf(ldf(W1, k0 * TABW + col, isf)) : (short)0;
        B1[jj] = (col < TABW && k1 < EMB_D)
                     ? f2bf(ldf(W1, k1 * TABW + col, isf)) : (short)0;
      }
      sB[L][nt * 2]     = *(const int4*)&B0;
      sB[L][nt * 2 + 1] = *(const int4*)&B1;
    }
  }
  float bi[4];
#pragma unroll
  for (int nt = 0; nt < 4; ++nt) {
    const int col = nt * 16 + c;
    bi[nt] = (col < TABW) ? ldf(b1, col, isf) : 0.f;
  }
  __syncthreads();

  for (int tile = wid; tile < NTILE; tile += BBLK * 4) {
    const int v0 = tile * 16;
    sh8 A0, A1;
#pragma unroll
    for (int jj = 0; jj < 8; ++jj) { A0[jj] = 0; A1[jj] = 0; }
    if (!isf) {
      const unsigned short* eb = (const unsigned short*)emb;
      const size_t rb = (size_t)(v0 + c) * EMB_D;
#pragma unroll
      for (int i = 0; i < 4; ++i) {
        unsigned d = *(const unsigned*)(eb + rb + q * 8 + 2 * i);
        A0[2 * i] = (short)(d & 0xffff); A0[2 * i + 1] = (short)(d >> 16);
      }
      const int k1b = 32 + q * 8;
#pragma unroll
      for (int i = 0; i < 4; ++i) {
        const int k = k1b + 2 * i;
        if (k + 1 < EMB_D) {
          unsigned d = *(const unsigned*)(eb + rb + k);
          A1[2 * i] = (short)(d & 0xffff); A1[2 * i + 1] = (short)(d >> 16);
        }
      }
    } else {
      const float* ef = (const float*)emb;
      const size_t rb = (size_t)(v0 + c) * EMB_D;
#pragma unroll
      for (int jj = 0; jj < 8; ++jj) {
        const int k0 = q * 8 + jj, k1 = 32 + q * 8 + jj;
        A0[jj] = f2bf(ef[rb + k0]);
        A1[jj] = (k1 < EMB_D) ? f2bf(ef[rb + k1]) : (short)0;
      }
    }
#pragma unroll
    for (int nt = 0; nt < 4; ++nt) {
      int4 b0i = sB[L][nt * 2], b1i = sB[L][nt * 2 + 1];
      sh8 B0 = *(const sh8*)&b0i, B1 = *(const sh8*)&b1i;
      const int col = nt * 16 + c;
      f4 acc = { bi[nt], bi[nt], bi[nt], bi[nt] };
      acc = __builtin_amdgcn_mfma_f32_16x16x32_bf16(A0, B0, acc, 0, 0, 0);
      acc = __builtin_amdgcn_mfma_f32_16x16x32_bf16(A1, B1, acc, 0, 0, 0);
      if (col < TABW) {
        const float s = gsc(col);
#pragma unroll
        for (int r = 0; r < 4; ++r)
          tab16[(size_t)(v0 + q * 4 + r) * TABW + col] =
              __half_as_ushort(__float2half_rn(acc[r] * s));
      }
    }
  }
}

// ONE batch element per wave; 100-step GRU in inline asm (r24 base, 119.9us).
// ROUND-26: hide the h-broadcast LDS roundtrip. r25 taught: lgkmcnt is
// shared, so intra-wave overlap needs COUNTED waits; and the half-boundary
// write->read->lgkm(0) roundtrip (~60-100cyc) is the largest exposed
// latency. Changes (scheduling/layout only, arithmetic bit-identical):
// (1) h1/h2 regions merged (h2 at +40, trash at +80): 6 reads -> 5x b128
//     landing exactly in v56-v75 (dot code unchanged).
// (2) tail leaves 7 DS tokens (2 wr + 5 rd); half-top waits lgkm(2) ->
//     h1 pairs valid -> run 20 h1-dependent dots (v44,v51 chains);
//     lgkm(0) only before the v52 chain. h2-read latency hides under dots.
// (3) SMEM s_loads always retired by a prior lgkm(0) -> counted waits see
//     pure in-order DS. Prologue writes h2-zero region for iteration 1.
__global__ __launch_bounds__(256, 5) void gru_main(
    const int* __restrict__ x, const float* __restrict__ ws,
    const void* __restrict__ emb, void* __restrict__ out)
{
  const int isf = detect_isf(emb);   // output dtype only
  const int j = threadIdx.x & 63;
  const int e = __builtin_amdgcn_readfirstlane(blockIdx.x * 4 + (threadIdx.x >> 6));
  const int jc = j < TABW ? j : 0;

  const int* xr = x + (size_t)e * SEQ_T;
  const unsigned short* tab = (const unsigned short*)(ws + OFF_TAB);
  const int o1 = jc * 40;                    // 10 packed dwords per column
  const int jc2 = jc * 2;                    // byte offset of col jc in f16 tab row
  const int a1 = ((j - 20) & 63) * 4;        // bpermute addr: r -> h-lanes
  const int a2 = ((j + 40) & 63) * 4;        // bpermute addr: hc -> z-lanes
  const float br1 = ws[OFF_B1 + 60 + jc];    // prescaled
  const float bi2 = ws[OFF_B2 + jc];         // prescaled
  const float br2 = ws[OFF_B2 + 60 + jc];    // prescaled

  // per-wave LDS 256B: h1 pairs bytes 0-39, h2 pairs 40-79, trash 80-166.
  // write maps: lane k<20 -> h1 @2k, h2 @40+2k; lanes 20-63 -> trash.
  // 5x uniform ds_read_b128 cover bytes 0-79 -> v56..v75 exactly.
  __shared__ char sbuf[1024];
  const unsigned lb = (unsigned)(uintptr_t)&sbuf[0] + (threadIdx.x >> 6) * 256;
  const int lmapT = 80 + 2 * (j - 20);
  const int wadA = (int)(lb + (j < 20 ? 2 * j : lmapT));
  const int wadB = (int)(lb + (j < 20 ? 40 + 2 * j : lmapT));
  const int rad = (int)lb;
  float h2out;

  asm volatile(
    // ---- packed f16 weights: U1P v10-19, W2P v20-29, U2P v30-39 ----
    "global_load_dwordx4 v[10:13], %[o1], %[wsp] offset:0\n\t"
    "global_load_dwordx4 v[14:17], %[o1], %[wsp] offset:16\n\t"
    "global_load_dwordx2 v[18:19], %[o1], %[wsp] offset:32\n\t"
    "v_add_u32 v44, 0x960, %[o1]\n\t"
    "v_add_u32 v45, 0x12c0, %[o1]\n\t"
    "global_load_dwordx4 v[20:23], v44, %[wsp] offset:0\n\t"
    "global_load_dwordx4 v[24:27], v44, %[wsp] offset:16\n\t"
    "global_load_dwordx2 v[28:29], v44, %[wsp] offset:32\n\t"
    "global_load_dwordx4 v[30:33], v45, %[wsp] offset:0\n\t"
    "global_load_dwordx4 v[34:37], v45, %[wsp] offset:16\n\t"
    "global_load_dwordx2 v[38:39], v45, %[wsp] offset:32\n\t"
    // ---- h masters zero ----
    "v_mov_b32 v40, 0\n\t"
    "v_mov_b32 v41, 0\n\t"
    // ---- prime: mx0->v52, mx1->v42, mx2->v43 (raw f16); idx3/4->s65/s68 --
    "s_load_dword s65, %[xp], 0x0\n\t"
    "s_load_dword s66, %[xp], 0x4\n\t"
    "s_load_dword s68, %[xp], 0x8\n\t"
    "s_waitcnt lgkmcnt(0)\n\t"
    "s_mul_i32 s65, s65, 120\n\t"
    "s_mul_i32 s66, s66, 120\n\t"
    "s_mul_i32 s68, s68, 120\n\t"
    "v_add_u32 v50, s65, %[jc2]\n\t"
    "global_load_ushort v52, v50, %[tabp]\n\t"
    "v_add_u32 v50, s66, %[jc2]\n\t"
    "global_load_ushort v42, v50, %[tabp]\n\t"
    "v_add_u32 v50, s68, %[jc2]\n\t"
    "global_load_ushort v43, v50, %[tabp]\n\t"
    "s_load_dword s65, %[xp], 0xc\n\t"     // idx3 (odd stream)
    "s_load_dword s68, %[xp], 0x10\n\t"    // idx4 (even stream)
    "s_movk_i32 s64, 0x14\n\t"             // next odd x-offset (idx5)
    "s_movk_i32 s69, 0x18\n\t"             // next even x-offset (idx6)
    "s_movk_i32 s67, 0x32\n\t"             // 50 unrolled iterations
    "s_waitcnt vmcnt(2)\n\t"               // weights + mx0 ready
    "v_cvt_f32_f16 v52, v52\n\t"           // mx0 -> f32 (prescaled)
    // ======== PROLOGUE: L1(0)  (h1(-1)=0 -> mh = br1'; mx0 = v52) ========
    "v_mov_b32 v44, %[br1]\n\t"
    "v_add_f32 v45, v52, v44\n\t"
    "v_exp_f32 v45, v45\n\t"
    "s_nop 1\n\t"
    "v_add_f32 v45, 1.0, v45\n\t"
    "v_rcp_f32 v45, v45\n\t"
    "s_nop 1\n\t"
    "ds_bpermute_b32 v46, %[a1], v45\n\t"
    "s_waitcnt lgkmcnt(0)\n\t"
    "v_fma_f32 v47, v46, v44, v52\n\t"
    "v_exp_f32 v47, v47\n\t"
    "s_nop 1\n\t"
    "v_add_f32 v47, 1.0, v47\n\t"
    "v_rcp_f32 v47, v47\n\t"
    "s_nop 1\n\t"
    "v_fma_f32 v47, -2.0, v47, 1.0\n\t"
    "ds_bpermute_b32 v46, %[a2], v47\n\t"
    "s_waitcnt lgkmcnt(0)\n\t"
    "v_sub_f32 v48, v40, v46\n\t"
    "v_fma_f32 v40, v45, v48, v46\n\t"     // h1(0)
    "v_cvt_f16_f32 v46, v40\n\t"
    "v_mov_b32 v54, 0\n\t"                 // h2(-1) = 0 region
    "ds_write_b16 %[wadA], v46\n\t"
    "ds_write_b16 %[wadB], v54\n\t"
    "ds_read_b128 v[56:59], %[rad]\n\t"
    "ds_read_b128 v[60:63], %[rad] offset:16\n\t"
    "ds_read_b128 v[64:67], %[rad] offset:32\n\t"
    "ds_read_b128 v[68:71], %[rad] offset:48\n\t"
    "ds_read_b128 v[72:75], %[rad] offset:64\n\t"
    // ======== LOOP k=0..49 ======== (7 DS tokens outstanding at top)
    "0:\n\t"
    // ---- HALF A: L2(2k) || L1(2k+1). h1 pairs v56-65, h2 pairs v66-75.
    "s_waitcnt lgkmcnt(2)\n\t"             // wA,wB,r1,r2,r3 done: h1 valid
    "v_dot2_f32_f16 v44, v56, v10, %[br1]\n\t"
    "v_dot2_f32_f16 v51, v56, v20, %[bi2]\n\t"
    "v_dot2_f32_f16 v44, v57, v11, v44\n\t"
    "v_dot2_f32_f16 v51, v57, v21, v51\n\t"
    "v_dot2_f32_f16 v44, v58, v12, v44\n\t"
    "v_dot2_f32_f16 v51, v58, v22, v51\n\t"
    "v_dot2_f32_f16 v44, v59, v13, v44\n\t"
    "v_dot2_f32_f16 v51, v59, v23, v51\n\t"
    "v_dot2_f32_f16 v44, v60, v14, v44\n\t"
    "v_dot2_f32_f16 v51, v60, v24, v51\n\t"
    "s_waitcnt lgkmcnt(0)\n\t"             // r4,r5 done: h2 valid
    "v_dot2_f32_f16 v52, v66, v30, %[br2]\n\t"
    "v_dot2_f32_f16 v44, v61, v15, v44\n\t"
    "v_dot2_f32_f16 v51, v61, v25, v51\n\t"
    "v_dot2_f32_f16 v52, v67, v31, v52\n\t"
    "v_dot2_f32_f16 v44, v62, v16, v44\n\t"
    "v_dot2_f32_f16 v51, v62, v26, v51\n\t"
    "v_dot2_f32_f16 v52, v68, v32, v52\n\t"
    "v_dot2_f32_f16 v44, v63, v17, v44\n\t"
    "v_dot2_f32_f16 v51, v63, v27, v51\n\t"
    "v_dot2_f32_f16 v52, v69, v33, v52\n\t"
    "v_dot2_f32_f16 v44, v64, v18, v44\n\t"
    "v_dot2_f32_f16 v51, v64, v28, v51\n\t"
    "v_dot2_f32_f16 v52, v70, v34, v52\n\t"
    "v_dot2_f32_f16 v44, v65, v19, v44\n\t"
    "v_dot2_f32_f16 v51, v65, v29, v51\n\t"
    "v_dot2_f32_f16 v52, v71, v35, v52\n\t"
    "v_dot2_f32_f16 v52, v72, v36, v52\n\t"
    "v_dot2_f32_f16 v52, v73, v37, v52\n\t"
    "v_dot2_f32_f16 v52, v74, v38, v52\n\t"
    "v_dot2_f32_f16 v52, v75, v39, v52\n\t"
    "s_waitcnt vmcnt(1)\n\t"               // mx(2k+1) raw f16 in v42
    "v_cvt_f32_f16 v42, v42\n\t"
    "v_add_f32 v45, v42, v44\n\t"
    "v_add_f32 v53, v51, v52\n\t"
    "v_exp_f32 v45, v45\n\t"
    "v_exp_f32 v53, v53\n\t"
    "v_add_f32 v45, 1.0, v45\n\t"
    "v_add_f32 v53, 1.0, v53\n\t"
    "v_rcp_f32 v45, v45\n\t"
    "v_rcp_f32 v53, v53\n\t"
    "ds_bpermute_b32 v46, %[a1], v45\n\t"
    "ds_bpermute_b32 v54, %[a1], v53\n\t"
    "s_mul_i32 s66, s65, 120\n\t"
    "v_add_u32 v50, s66, %[jc2]\n\t"
    "s_waitcnt lgkmcnt(0)\n\t"
    "v_fma_f32 v47, v46, v44, v42\n\t"     // hp1, last v42 use
    "v_fma_f32 v55, v54, v52, v51\n\t"     // hp2
    "global_load_ushort v42, v50, %[tabp]\n\t"  // mx(2k+3)
    "s_min_u32 s64, s64, 396\n\t"
    "s_load_dword s65, %[xp], s64\n\t"     // idx(2k+5)
    "s_add_u32 s64, s64, 8\n\t"
    "v_exp_f32 v47, v47\n\t"
    "v_exp_f32 v55, v55\n\t"
    "v_add_f32 v47, 1.0, v47\n\t"
    "v_add_f32 v55, 1.0, v55\n\t"
    "v_rcp_f32 v47, v47\n\t"
    "v_rcp_f32 v55, v55\n\t"
    "s_nop 0\n\t"
    "v_fma_f32 v47, -2.0, v47, 1.0\n\t"    // hc1
    "v_fma_f32 v55, -2.0, v55, 1.0\n\t"    // hc2
    "ds_bpermute_b32 v46, %[a2], v47\n\t"
    "ds_bpermute_b32 v54, %[a2], v55\n\t"
    "s_waitcnt lgkmcnt(0)\n\t"             // bperms + s_load retired
    "v_sub_f32 v48, v40, v46\n\t"
    "v_fma_f32 v40, v45, v48, v46\n\t"     // h1(2k+1)
    "v_sub_f32 v48, v41, v54\n\t"
    "v_fma_f32 v41, v53, v48, v54\n\t"     // h2(2k)
    "v_cvt_f16_f32 v46, v40\n\t"
    "v_cvt_f16_f32 v54, v41\n\t"
    "ds_write_b16 %[wadA], v46\n\t"
    "ds_write_b16 %[wadB], v54\n\t"
    "ds_read_b128 v[56:59], %[rad]\n\t"
    "ds_read_b128 v[60:63], %[rad] offset:16\n\t"
    "ds_read_b128 v[64:67], %[rad] offset:32\n\t"
    "ds_read_b128 v[68:71], %[rad] offset:48\n\t"
    "ds_read_b128 v[72:75], %[rad] offset:64\n\t"
    // ---- HALF B: L2(2k+1) || L1(2k+2). mx = v43. ----
    "s_waitcnt lgkmcnt(2)\n\t"
    "v_dot2_f32_f16 v44, v56, v10, %[br1]\n\t"
    "v_dot2_f32_f16 v51, v56, v20, %[bi2]\n\t"
    "v_dot2_f32_f16 v44, v57, v11, v44\n\t"
    "v_dot2_f32_f16 v51, v57, v21, v51\n\t"
    "v_dot2_f32_f16 v44, v58, v12, v44\n\t"
    "v_dot2_f32_f16 v51, v58, v22, v51\n\t"
    "v_dot2_f32_f16 v44, v59, v13, v44\n\t"
    "v_dot2_f32_f16 v51, v59, v23, v51\n\t"
    "v_dot2_f32_f16 v44, v60, v14, v44\n\t"
    "v_dot2_f32_f16 v51, v60, v24, v51\n\t"
    "s_waitcnt lgkmcnt(0)\n\t"
    "v_dot2_f32_f16 v52, v66, v30, %[br2]\n\t"
    "v_dot2_f32_f16 v44, v61, v15, v44\n\t"
    "v_dot2_f32_f16 v51, v61, v25, v51\n\t"
    "v_dot2_f32_f16 v52, v67, v31, v52\n\t"
    "v_dot2_f32_f16 v44, v62, v16, v44\n\t"
    "v_dot2_f32_f16 v51, v62, v26, v51\n\t"
    "v_dot2_f32_f16 v52, v68, v32, v52\n\t"
    "v_dot2_f32_f16 v44, v63, v17, v44\n\t"
    "v_dot2_f32_f16 v51, v63, v27, v51\n\t"
    "v_dot2_f32_f16 v52, v69, v33, v52\n\t"
    "v_dot2_f32_f16 v44, v64, v18, v44\n\t"
    "v_dot2_f32_f16 v51, v64, v28, v51\n\t"
    "v_dot2_f32_f16 v52, v70, v34, v52\n\t"
    "v_dot2_f32_f16 v44, v65, v19, v44\n\t"
    "v_dot2_f32_f16 v51, v65, v29, v51\n\t"
    "v_dot2_f32_f16 v52, v71, v35, v52\n\t"
    "v_dot2_f32_f16 v52, v72, v36, v52\n\t"
    "v_dot2_f32_f16 v52, v73, v37, v52\n\t"
    "v_dot2_f32_f16 v52, v74, v38, v52\n\t"
    "v_dot2_f32_f16 v52, v75, v39, v52\n\t"
    "s_waitcnt vmcnt(1)\n\t"               // mx(2k+2) raw f16 in v43
    "v_cvt_f32_f16 v43, v43\n\t"
    "v_add_f32 v45, v43, v44\n\t"
    "v_add_f32 v53, v51, v52\n\t"
    "v_exp_f32 v45, v45\n\t"
    "v_exp_f32 v53, v53\n\t"
    "v_add_f32 v45, 1.0, v45\n\t"
    "v_add_f32 v53, 1.0, v53\n\t"
    "v_rcp_f32 v45, v45\n\t"
    "v_rcp_f32 v53, v53\n\t"
    "ds_bpermute_b32 v46, %[a1], v45\n\t"
    "ds_bpermute_b32 v54, %[a1], v53\n\t"
    "s_mul_i32 s66, s68, 120\n\t"
    "v_add_u32 v50, s66, %[jc2]\n\t"
    "s_waitcnt lgkmcnt(0)\n\t"
    "v_fma_f32 v47, v46, v44, v43\n\t"     // hp1, last v43 use
    "v_fma_f32 v55, v54, v52, v51\n\t"     // hp2
    "global_load_ushort v43, v50, %[tabp]\n\t"  // mx(2k+4)
    "s_min_u32 s69, s69, 392\n\t"
    "s_load_dword s68, %[xp], s69\n\t"     // idx(2k+6)
    "s_add_u32 s69, s69, 8\n\t"
    "v_exp_f32 v47, v47\n\t"
    "v_exp_f32 v55, v55\n\t"
    "v_add_f32 v47, 1.0, v47\n\t"
    "v_add_f32 v55, 1.0, v55\n\t"
    "v_rcp_f32 v47, v47\n\t"
    "v_rcp_f32 v55, v55\n\t"
    "s_nop 0\n\t"
    "v_fma_f32 v47, -2.0, v47, 1.0\n\t"
    "v_fma_f32 v55, -2.0, v55, 1.0\n\t"
    "ds_bpermute_b32 v46, %[a2], v47\n\t"
    "ds_bpermute_b32 v54, %[a2], v55\n\t"
    "s_waitcnt lgkmcnt(0)\n\t"
    "v_sub_f32 v48, v40, v46\n\t"
    "v_fma_f32 v40, v45, v48, v46\n\t"     // h1(2k+2)
    "v_sub_f32 v48, v41, v54\n\t"
    "v_fma_f32 v41, v53, v48, v54\n\t"     // h2(2k+1)
    "v_cvt_f16_f32 v46, v40\n\t"
    "v_cvt_f16_f32 v54, v41\n\t"
    "ds_write_b16 %[wadA], v46\n\t"
    "ds_write_b16 %[wadB], v54\n\t"
    "ds_read_b128 v[56:59], %[rad]\n\t"
    "ds_read_b128 v[60:63], %[rad] offset:16\n\t"
    "ds_read_b128 v[64:67], %[rad] offset:32\n\t"
    "ds_read_b128 v[68:71], %[rad] offset:48\n\t"
    "ds_read_b128 v[72:75], %[rad] offset:64\n\t"
    "s_sub_u32 s67, s67, 1\n\t"
    "s_cmp_lg_u32 s67, 0\n\t"
    "s_cbranch_scc1 0b\n\t"
    "s_waitcnt vmcnt(0) lgkmcnt(0)\n\t"
    "v_mov_b32 %[h2o], v41\n\t"
    : [h2o] "=v"(h2out)
    : [wsp] "s"(ws), [xp] "s"(xr), [tabp] "s"(tab),
      [o1] "v"(o1), [jc2] "v"(jc2), [a1] "v"(a1), [a2] "v"(a2),
      [br1] "v"(br1), [bi2] "v"(bi2), [br2] "v"(br2),
      [wadA] "v"(wadA), [wadB] "v"(wadB), [rad] "v"(rad)
    : "memory", "vcc", "scc",
      "v10","v11","v12","v13","v14","v15","v16","v17","v18","v19",
      "v20","v21","v22","v23","v24","v25","v26","v27","v28","v29",
      "v30","v31","v32","v33","v34","v35","v36","v37","v38","v39",
      "v40","v41","v42","v43","v44","v45","v46","v47","v48","v50",
      "v51","v52","v53","v54","v55",
      "v56","v57","v58","v59","v60","v61","v62","v63","v64","v65",
      "v66","v67","v68","v69","v70","v71","v72","v73","v74","v75",
      "s64","s65","s66","s67","s68","s69");

  // ---- dense: logits = h2 @ Wd + bd (h2 master fp32 in lanes 0..19) ----
  if (j < 15) {
    float a = ws[OFF_BD + j];
#pragma unroll
    for (int k = 0; k < HID; ++k)
      a = fmaf(rdl(h2out, k), ws[OFF_WD + k * 15 + j], a);
    if (isf) ((float*)out)[(size_t)e * 15 + j] = a;
    else ((__hip_bfloat16*)out)[(size_t)e * 15 + j] = __float2bfloat16(a);
  }
}

extern "C" void kernel_launch(void* const* d_in, const int* in_sizes, int n_in,
                              void* d_out, int out_size, void* d_ws, size_t ws_size,
                              hipStream_t stream) {
  const int* x    = (const int*)d_in[0];
  const void* emb = d_in[1];
  const void* W1  = d_in[2];
  const void* U1  = d_in[3];
  const void* b1  = d_in[4];
  const void* W2  = d_in[5];
  const void* U2  = d_in[6];
  const void* b2  = d_in[7];
  const void* Wd  = d_in[8];
  const void* bd  = d_in[9];
  float* ws = (float*)d_ws;   // 6.02 MB used (12 MB proven safe)

  build_table<<<BBLK, 256, 0, stream>>>(
      emb, W1, b1, U1, W2, U2, b2, Wd, bd, ws);
  gru_main<<<2048, 256, 0, stream>>>(x, ws, emb, d_out);
}